// Round 5
// baseline (221.917 us; speedup 1.0000x reference)
//
#include <hip/hip_runtime.h>
#include <hip/hip_bf16.h>

// ContrastiveLoss: z (8192x1024 fp32) -> scalar
//   zn = z / max(||z||,eps); S = zn@zn^T; diag=MASK; /T; nll = -S[i,i^4096] + lse(S[i,:]); mean
// R5: fp8 e4m3 GEMM (zn scaled x32 into e4m3 normal range). 256x256 lower-tri
// tiles, BK=128 stages double-buffered in 128KB LDS, 128B rows + chunk^(row&7)
// swizzle (R4-verified 0 conflicts), ds_read_b64 fragments, 16x16x32 fp8 MFMA.
// Finale fused into k_tile via agent-scope completion counter (no k_final).

#define N 8192
#define D 1024
#define INV_T 14.285714285714286f
#define NTILES 528
#define ACC_SCALE (INV_T / 1024.0f)  // undo fp8 x32 scaling on both operands

typedef float f32x4 __attribute__((ext_vector_type(4)));

__device__ inline void gload16(const void* g, void* l) {
  __builtin_amdgcn_global_load_lds(
      (const __attribute__((address_space(1))) void*)g,
      (__attribute__((address_space(3))) void*)l, 16, 0, 0);
}

// Phase 1: row-normalize z, scale x32, cast fp8 e4m3 -> zn8; zero rowsum/counter.
__global__ __launch_bounds__(256) void k_normalize(const float* __restrict__ z,
                                                   unsigned char* __restrict__ zn8,
                                                   float* __restrict__ rowsum,
                                                   int* __restrict__ counter) {
  const int row = blockIdx.x;
  const int t = threadIdx.x;
  if (row < 32) rowsum[row * 256 + t] = 0.0f;
  if (row == 32 && t == 0) *counter = 0;
  const float4 v = ((const float4*)(z + (size_t)row * D))[t];
  float ss = v.x * v.x + v.y * v.y + v.z * v.z + v.w * v.w;
#pragma unroll
  for (int off = 32; off > 0; off >>= 1) ss += __shfl_down(ss, off, 64);
  __shared__ float red[4];
  __shared__ float s_inv;
  if ((t & 63) == 0) red[t >> 6] = ss;
  __syncthreads();
  if (t == 0) {
    float tot = red[0] + red[1] + red[2] + red[3];
    s_inv = 1.0f / fmaxf(sqrtf(tot), 1e-8f);
  }
  __syncthreads();
  const float sc = s_inv * 32.0f;  // e4m3 normal range; undone by ACC_SCALE
  int p = __builtin_amdgcn_cvt_pk_fp8_f32(v.x * sc, v.y * sc, 0, false);
  p = __builtin_amdgcn_cvt_pk_fp8_f32(v.z * sc, v.w * sc, p, true);
  ((int*)(zn8 + (size_t)row * D))[t] = p;
}

// Phase 2: 256x256 lower-triangle tile per block, 512 threads (8 waves, 4x2).
// fp8 BK=128: per buffer A 32KB + B 32KB; double-buffered = 128KB dynamic LDS.
// Rows 128B (8 x 16B chunks), logical chunk c at phys c^(r&7): same geometry
// R4 measured at 0 conflicts; b64 fragment reads are bank-uniform (4 lanes per
// 2-bank slot = exact minimum cycles for 512B/wave).
__global__ __launch_bounds__(512, 2) void k_tile(const unsigned char* __restrict__ zn8,
                                                 float* __restrict__ rowsum,
                                                 float* __restrict__ pos,
                                                 int* __restrict__ counter,
                                                 float* __restrict__ out) {
  extern __shared__ __align__(16) char smem[];  // 131072
  const int tid = threadIdx.x;
  const int w = tid >> 6, l = tid & 63;

  // decode blockIdx -> lower-triangle (tr, tc), tr >= tc, over 32x32 tile grid
  const int b = blockIdx.x;
  int tr = (int)((sqrtf(8.0f * (float)b + 1.0f) - 1.0f) * 0.5f);
  if (tr * (tr + 1) / 2 > b) --tr;
  if ((tr + 1) * (tr + 2) / 2 <= b) ++tr;
  const int tc = b - tr * (tr + 1) / 2;
  const bool diag = (tr == tc);

  const int wr = w >> 1, wc = w & 1;
  const int m = l & 15, kg = l >> 4;
  const int rowA0 = tr * 256, colB0 = tc * 256;

  f32x4 acc[4][8] = {};

  // staging: per matrix per stage 2048 slots x 16B (256 rows x 8 chunks).
  // phys slot s -> row s>>3, phys chunk s&7 holds logical chunk (s&7)^(row&7).
  int srow[4], scol[4];
#pragma unroll
  for (int j = 0; j < 4; ++j) {
    int s = j * 512 + tid;
    int r = s >> 3;
    srow[j] = r;
    scol[j] = (s & 7) ^ (r & 7);
  }

  // prologue: stage kt=0 into buffer 0
  {
    char* ab = smem;
    char* bb = smem + 32768;
#pragma unroll
    for (int j = 0; j < 4; ++j) {
      const int s = j * 512 + tid;
      gload16((const char*)zn8 + ((size_t)(rowA0 + srow[j]) * D + scol[j] * 16), ab + s * 16);
    }
    if (!diag) {
#pragma unroll
      for (int j = 0; j < 4; ++j) {
        const int s = j * 512 + tid;
        gload16((const char*)zn8 + ((size_t)(colB0 + srow[j]) * D + scol[j] * 16), bb + s * 16);
      }
    }
  }
  __syncthreads();

  for (int kt = 0; kt < 8; ++kt) {
    if (kt < 7) {  // async prefetch kt+1 into other buffer; overlaps MFMA below
      const size_t kb = (size_t)(kt + 1) * 128;
      char* ab = smem + ((kt + 1) & 1) * 65536;
#pragma unroll
      for (int j = 0; j < 4; ++j) {
        const int s = j * 512 + tid;
        gload16((const char*)zn8 + ((size_t)(rowA0 + srow[j]) * D + kb + scol[j] * 16), ab + s * 16);
      }
      if (!diag) {
        char* bb = ab + 32768;
#pragma unroll
        for (int j = 0; j < 4; ++j) {
          const int s = j * 512 + tid;
          gload16((const char*)zn8 + ((size_t)(colB0 + srow[j]) * D + kb + scol[j] * 16), bb + s * 16);
        }
      }
    }
    const char* ab = smem + (kt & 1) * 65536;
    const char* bb = diag ? ab : (ab + 32768);
#pragma unroll
    for (int ks = 0; ks < 4; ++ks) {  // K=32 fp8 per MFMA step
      long af[4], bfr[8];
      // lane (m,kg) wants 8B at logical row-offset ks*32 + kg*8:
      // chunk c = 2*ks + (kg>>1), phys = (c ^ (m&7))*16 + (kg&1)*8  (r&7 == m&7)
      const int csw = ((2 * ks + (kg >> 1)) ^ (m & 7)) * 16 + (kg & 1) * 8;
#pragma unroll
      for (int mt = 0; mt < 4; ++mt)
        af[mt] = *(const long*)(ab + (wr * 64 + mt * 16 + m) * 128 + csw);
#pragma unroll
      for (int nt = 0; nt < 8; ++nt)
        bfr[nt] = *(const long*)(bb + (wc * 128 + nt * 16 + m) * 128 + csw);
#pragma unroll
      for (int mt = 0; mt < 4; ++mt)
#pragma unroll
        for (int nt = 0; nt < 8; ++nt)
          acc[mt][nt] = __builtin_amdgcn_mfma_f32_16x16x32_fp8_fp8(af[mt], bfr[nt], acc[mt][nt], 0, 0, 0);
    }
    __syncthreads();  // drains prefetch (vmcnt) + guards buffer reuse
  }

  // Epilogue. C/D layout: col=l&15, row=(l>>4)*4+reg.
  const int quad = l >> 4;
  const int col = l & 15;
  float cs[8] = {0.f, 0.f, 0.f, 0.f, 0.f, 0.f, 0.f, 0.f};
#pragma unroll
  for (int mt = 0; mt < 4; ++mt) {
    float rs[4] = {0.f, 0.f, 0.f, 0.f};
#pragma unroll
    for (int nt = 0; nt < 8; ++nt) {
      const int gcol = colB0 + wc * 128 + nt * 16 + col;
#pragma unroll
      for (int r = 0; r < 4; ++r) {
        const int grow = rowA0 + wr * 64 + mt * 16 + quad * 4 + r;
        const float t = acc[mt][nt][r] * ACC_SCALE;
        if (gcol == (grow ^ (N / 2))) {  // pos pair; never in diag tiles
          // agent-scope stores so the fused finale (any XCD) sees them
          __hip_atomic_store(&pos[grow], t, __ATOMIC_RELAXED, __HIP_MEMORY_SCOPE_AGENT);
          __hip_atomic_store(&pos[gcol], t, __ATOMIC_RELAXED, __HIP_MEMORY_SCOPE_AGENT);
        }
        const float e = (gcol == grow) ? 0.0f : __expf(t - INV_T);
        rs[r] += e;
        cs[nt] += e;
      }
    }
#pragma unroll
    for (int off = 1; off < 16; off <<= 1) {
#pragma unroll
      for (int r = 0; r < 4; ++r) rs[r] += __shfl_xor(rs[r], off, 64);
    }
    if (col == 0) {
#pragma unroll
      for (int r = 0; r < 4; ++r)
        atomicAdd(&rowsum[rowA0 + wr * 64 + mt * 16 + quad * 4 + r], rs[r]);
    }
  }
  if (!diag) {  // col sums = row-sums for block tc rows (symmetry)
#pragma unroll
    for (int nt = 0; nt < 8; ++nt) {
      cs[nt] += __shfl_xor(cs[nt], 16, 64);
      cs[nt] += __shfl_xor(cs[nt], 32, 64);
    }
    if (l < 16) {
#pragma unroll
      for (int nt = 0; nt < 8; ++nt)
        atomicAdd(&rowsum[colB0 + wc * 128 + nt * 16 + l], cs[nt]);
    }
  }

  // Fused finale: last block to finish computes out = mean(-pos + C + log(rowsum)).
  __shared__ int s_last;
  __syncthreads();     // all this block's atomics issued & drained
  __threadfence();     // device-scope release
  if (tid == 0) {
    int old = __hip_atomic_fetch_add(counter, 1, __ATOMIC_ACQ_REL, __HIP_MEMORY_SCOPE_AGENT);
    s_last = (old == NTILES - 1);
  }
  __syncthreads();
  if (s_last) {
    float s = 0.f;
    for (int i = tid; i < N; i += 512) {
      const float rsv = __hip_atomic_load(&rowsum[i], __ATOMIC_RELAXED, __HIP_MEMORY_SCOPE_AGENT);
      const float pv = __hip_atomic_load(&pos[i], __ATOMIC_RELAXED, __HIP_MEMORY_SCOPE_AGENT);
      s += INV_T + __logf(rsv) - pv;
    }
#pragma unroll
    for (int off = 32; off > 0; off >>= 1) s += __shfl_down(s, off, 64);
    float* red = (float*)smem;
    if (l == 0) red[w] = s;
    __syncthreads();
    if (tid == 0) {
      float tot = 0.f;
#pragma unroll
      for (int j = 0; j < 8; ++j) tot += red[j];
      out[0] = tot * (1.0f / N);
    }
  }
}

extern "C" void kernel_launch(void* const* d_in, const int* in_sizes, int n_in,
                              void* d_out, int out_size, void* d_ws, size_t ws_size,
                              hipStream_t stream) {
  const float* z = (const float*)d_in[0];
  float* out = (float*)d_out;
  char* ws = (char*)d_ws;
  unsigned char* zn8 = (unsigned char*)ws;                      // 8 MiB fp8
  float* rowsum = (float*)(ws + (size_t)N * D);                 // 32 KiB
  float* pos = (float*)(ws + (size_t)N * D + (size_t)N * 4);    // 32 KiB
  int* counter = (int*)(ws + (size_t)N * D + (size_t)N * 8);    // 4 B

  static bool attr_set = false;
  if (!attr_set) {  // host-side attribute, idempotent, not a stream op
    hipFuncSetAttribute((const void*)k_tile,
                        hipFuncAttributeMaxDynamicSharedMemorySize, 131072);
    attr_set = true;
  }

  k_normalize<<<N, 256, 0, stream>>>(z, zn8, rowsum, counter);
  k_tile<<<NTILES, 512, 131072, stream>>>(zn8, rowsum, pos, counter, out);
}